// Round 1
// 975.692 us; speedup vs baseline: 1.1545x; 1.1545x over previous
//
#include <hip/hip_runtime.h>

// LoRA Linear: out = x @ W^T + bias + (x @ a[idx]^T) @ b[idx]^T
// B=8, S=2048, D_IN=D_OUT=4096, RANK=16, N_ADAPTERS=8.
// R3: (1) gemm rebuilt as 256x256 8-phase deep-pipelined kernel (T1 XCD swizzle +
//     T2 LDS XOR-swizzle + T3/T4 counted vmcnt(6) + T5 setprio). 128 KiB LDS dbuf,
//     8 waves (2Mx4N), BK=64, stage order {Ah0,Bh0,Bh1}@P2-P4(t-2), Ah1@P1(t-1).
//     (2) inter path split: pure-streaming x conversion + K-split rank-16 MFMA
//     kernel (2048 blocks, bf16 x reads, 2 deterministic fp32 atomicAdds/elem).
// Workspace: x_bf16 128MiB + W_bf16 32MiB + inter 1MiB = 161MiB (unchanged).

#define DIN     4096
#define DOUT    4096
#define RANK    16
#define M_DIM   16384   // B*S
#define K_DIM   DIN
#define N_DIM   DOUT
#define BK      64
#define NT      (K_DIM / BK)     // 64 K-tiles
#define LDS_BYTES 131072

typedef __attribute__((ext_vector_type(8))) short  short8;
typedef __attribute__((ext_vector_type(4))) float  floatx4;

__device__ __forceinline__ unsigned short f2bf(float f) {
  union { float f; unsigned int u; } v; v.f = f;
  return (unsigned short)((v.u + 0x7FFFu + ((v.u >> 16) & 1u)) >> 16);
}
__device__ __forceinline__ unsigned int pk2(float a, float b) {
  return (unsigned int)f2bf(a) | ((unsigned int)f2bf(b) << 16);
}

// adapter_indices is int64 in the reference; harness contract says int32.
// int64 little-endian with values<8 looks like [v0,0,v1,0,...] as int32.
__device__ __forceinline__ int load_adapter(const int* __restrict__ p, int b) {
  bool i64 = (p[1] == 0) & (p[3] == 0) & (p[5] == 0) & (p[7] == 0);
  return i64 ? p[2 * b] : p[b];
}

__device__ __forceinline__ void async16(const unsigned short* g, void* s) {
  __builtin_amdgcn_global_load_lds(
      (const __attribute__((address_space(1))) void*)g,
      (__attribute__((address_space(3))) void*)s, 16, 0, 0);
}

// ---------- kernel 1: fp32 -> bf16 streaming (used for both W and x) ----------
__global__ __launch_bounds__(256) void conv_stream(const float* __restrict__ w,
                                                   unsigned short* __restrict__ wbf) {
  size_t base = ((size_t)blockIdx.x * 256 + threadIdx.x) * 8;
  const float4* src = (const float4*)(w + base);
  float4 f0 = src[0], f1 = src[1];
  uint4 p;
  p.x = pk2(f0.x, f0.y); p.y = pk2(f0.z, f0.w);
  p.z = pk2(f1.x, f1.y); p.w = pk2(f1.z, f1.w);
  *(uint4*)(wbf + base) = p;
}

// ---------- kernel 2: inter = x @ a^T via MFMA, K split 2 ways across grid ----
// grid (M/16, 2), 256 thr / 4 waves. Wave w: k in [blockIdx.y*2048 + w*512, +512).
// Block reduce 4 waves in LDS; wave 0 atomicAdds (2 commutative adds -> exact).
__global__ __launch_bounds__(256) void inter16(
    const unsigned short* __restrict__ xbf,
    const float* __restrict__ lora_a,
    const int* __restrict__ adapters,
    float* __restrict__ inter) {
  __shared__ floatx4 red[4][64];
  const int tid = threadIdx.x, wave = tid >> 6, lane = tid & 63;
  const int fr = lane & 15, fq = lane >> 4;
  const int row0 = blockIdx.x * 16;
  const int adapter = load_adapter(adapters, row0 >> 11);  // 2048 rows/batch
  const unsigned short* xp = xbf + (size_t)(row0 + fr) * DIN;
  const float* ap = lora_a + ((size_t)adapter * RANK + fr) * DIN;
  floatx4 acc = {};
  const int kbeg = blockIdx.y * 2048 + wave * 512;
#pragma unroll 2
  for (int k0 = kbeg; k0 < kbeg + 512; k0 += 32) {
    const int k = k0 + fq * 8;
    short8 xf = *(const short8*)(xp + k);      // x already bf16
    float4 b0 = *(const float4*)(ap + k);
    float4 b1 = *(const float4*)(ap + k + 4);
    uint4 bpk;
    bpk.x = pk2(b0.x, b0.y); bpk.y = pk2(b0.z, b0.w);
    bpk.z = pk2(b1.x, b1.y); bpk.w = pk2(b1.z, b1.w);
    acc = __builtin_amdgcn_mfma_f32_16x16x32_bf16(xf, *(short8*)&bpk, acc, 0, 0, 0);
  }
  red[wave][lane] = acc;
  __syncthreads();
  if (wave == 0) {
    floatx4 s = red[0][lane] + red[1][lane] + red[2][lane] + red[3][lane];
    // C/D layout: col(rank)=lane&15, row=fq*4+j
#pragma unroll
    for (int j = 0; j < 4; ++j)
      atomicAdd(&inter[(size_t)(row0 + fq * 4 + j) * RANK + fr], s[j]);
  }
}

// ---------- kernel 3: 256x256 8-phase bf16 GEMM + fused LoRA step + bias ------
#define SYNC_ENTER() do {                                   \
    __builtin_amdgcn_sched_barrier(0);                      \
    __builtin_amdgcn_s_barrier();                           \
    asm volatile("s_waitcnt lgkmcnt(0)" ::: "memory");      \
    __builtin_amdgcn_sched_barrier(0);                      \
    __builtin_amdgcn_s_setprio(1); } while (0)
#define SYNC_EXIT() do {                                    \
    __builtin_amdgcn_s_setprio(0);                          \
    __builtin_amdgcn_sched_barrier(0);                      \
    __builtin_amdgcn_s_barrier();                           \
    __builtin_amdgcn_sched_barrier(0); } while (0)

__global__ __launch_bounds__(512, 2) void gemm256(
    const unsigned short* __restrict__ A,    // x bf16 [M,K]
    const unsigned short* __restrict__ Bw,   // W bf16 [N,K] (row-major = B^T)
    const float* __restrict__ bias,          // [N]
    const float* __restrict__ inter,         // [M,16] fp32
    const float* __restrict__ lora_b,        // [8, N, 16] fp32
    const int* __restrict__ adapters,
    float* __restrict__ out) {               // [M,N] fp32
  extern __shared__ char lds[];
  const int tid  = threadIdx.x;
  const int lane = tid & 63, wave = tid >> 6;
  const int wm = wave >> 2, wn = wave & 3;   // 2 x 4 wave grid

  // T1: bijective XCD swizzle (1024 % 8 == 0)
  const int wg   = ((int)blockIdx.x & 7) * 128 + ((int)blockIdx.x >> 3);
  const int row0 = (wg >> 4) * 256;          // 64 M-tiles
  const int col0 = (wg & 15) * 256;          // 16 N-tiles (fastest: share A-panel)

  // ---- staging geometry. global_load_lds writes linear (base + lane*16B), so
  // the T2 swizzle (byte ^= (row&7)<<4) is applied by permuting the GLOBAL src:
  // LDS slot granule g' = lane&7 at row (wave*16 + c*8 + lane>>3) holds source
  // k-granule g = g' ^ (row&7) = (lane&7) ^ (lane>>3).
  const int sg = (lane & 7) ^ (lane >> 3);
  const int sr = wave * 16 + (lane >> 3);
  const unsigned short* pA0 = A  + (size_t)(row0 + sr) * K_DIM + sg * 8;
  const unsigned short* pB0 = Bw + (size_t)(col0 + sr) * K_DIM + sg * 8;
  char* const dA0 = lds + wave * 2048;       // wave-uniform dest base

#define STG_A(h, kt, buf) do {                                            \
    const unsigned short* _p = pA0 + (size_t)(h) * 128 * K_DIM + (kt) * BK; \
    char* _d = dA0 + (buf) * 65536 + (h) * 16384;                         \
    async16(_p, _d);                                                      \
    async16(_p + (size_t)8 * K_DIM, _d + 1024); } while (0)
#define STG_B(h, kt, buf) do {                                            \
    const unsigned short* _p = pB0 + (size_t)(h) * 128 * K_DIM + (kt) * BK; \
    char* _d = dA0 + 32768 + (buf) * 65536 + (h) * 16384;                 \
    async16(_p, _d);                                                      \
    async16(_p + (size_t)8 * K_DIM, _d + 1024); } while (0)

  // ---- fragment read geometry (16x16x32: A[m=lane&15][k=(lane>>4)*8+j])
  const int fr = lane & 15, fq = lane >> 4;
  const int swz = (fr & 7) << 4;
  const int kb0 = (fq * 16) ^ swz;           // ks=0 byte col (swizzled)
  const int kb1 = (64 + fq * 16) ^ swz;      // ks=1
  const int ar = wm * 64 + fr;               // A row base: +mt*16, +128 for hi
  const int br = wn * 32 + fr;               // B row base: +nt*16, +128 for hi

  floatx4 acc[8][4] = {};
  short8 a[4][2], bl[2][2], bh[2][2];

  // ---- prologue: tile0 all 4 halves -> buf0; {Ah0,Bh0,Bh1}(tile1) -> buf1
  STG_A(0, 0, 0); STG_B(0, 0, 0); STG_B(1, 0, 0); STG_A(1, 0, 0);
  STG_A(0, 1, 1); STG_B(0, 1, 1); STG_B(1, 1, 1);
  asm volatile("s_waitcnt vmcnt(6)" ::: "memory");   // tile0 resident
  __builtin_amdgcn_sched_barrier(0);
  __builtin_amdgcn_s_barrier();

  for (int t = 0; t < NT; ++t) {
    const int buf = t & 1, nbuf = buf ^ 1;
    const char* ab = lds + buf * 65536;
    const char* bb = ab + 32768;
    // ---- P1: read A-lo(m0-3) + B-lo(n0-1); stage Ah1(t+1) -> nbuf
#pragma unroll
    for (int mt = 0; mt < 4; ++mt) {
      a[mt][0] = *(const short8*)(ab + (ar + mt * 16) * 128 + kb0);
      a[mt][1] = *(const short8*)(ab + (ar + mt * 16) * 128 + kb1);
    }
#pragma unroll
    for (int nt = 0; nt < 2; ++nt) {
      bl[nt][0] = *(const short8*)(bb + (br + nt * 16) * 128 + kb0);
      bl[nt][1] = *(const short8*)(bb + (br + nt * 16) * 128 + kb1);
    }
    if (t + 1 < NT) STG_A(1, t + 1, nbuf);
    SYNC_ENTER();
#pragma unroll
    for (int mt = 0; mt < 4; ++mt)
#pragma unroll
      for (int nt = 0; nt < 2; ++nt) {
        acc[mt][nt] = __builtin_amdgcn_mfma_f32_16x16x32_bf16(a[mt][0], bl[nt][0], acc[mt][nt], 0, 0, 0);
        acc[mt][nt] = __builtin_amdgcn_mfma_f32_16x16x32_bf16(a[mt][1], bl[nt][1], acc[mt][nt], 0, 0, 0);
      }
    SYNC_EXIT();
    // ---- P2: read B-hi(n2-3); stage Ah0(t+2) -> buf (Ah0(t) drained at P1 bar)
#pragma unroll
    for (int nt = 0; nt < 2; ++nt) {
      bh[nt][0] = *(const short8*)(bb + (128 + br + nt * 16) * 128 + kb0);
      bh[nt][1] = *(const short8*)(bb + (128 + br + nt * 16) * 128 + kb1);
    }
    if (t + 2 < NT) STG_A(0, t + 2, buf);
    SYNC_ENTER();
#pragma unroll
    for (int mt = 0; mt < 4; ++mt)
#pragma unroll
      for (int nt = 0; nt < 2; ++nt) {
        acc[mt][2 + nt] = __builtin_amdgcn_mfma_f32_16x16x32_bf16(a[mt][0], bh[nt][0], acc[mt][2 + nt], 0, 0, 0);
        acc[mt][2 + nt] = __builtin_amdgcn_mfma_f32_16x16x32_bf16(a[mt][1], bh[nt][1], acc[mt][2 + nt], 0, 0, 0);
      }
    SYNC_EXIT();
    // ---- P3: read A-hi(m4-7, reuse a[]); stage Bh0(t+2) -> buf
#pragma unroll
    for (int mt = 0; mt < 4; ++mt) {
      a[mt][0] = *(const short8*)(ab + (128 + ar + mt * 16) * 128 + kb0);
      a[mt][1] = *(const short8*)(ab + (128 + ar + mt * 16) * 128 + kb1);
    }
    if (t + 2 < NT) STG_B(0, t + 2, buf);
    SYNC_ENTER();
#pragma unroll
    for (int mt = 0; mt < 4; ++mt)
#pragma unroll
      for (int nt = 0; nt < 2; ++nt) {
        acc[4 + mt][nt] = __builtin_amdgcn_mfma_f32_16x16x32_bf16(a[mt][0], bl[nt][0], acc[4 + mt][nt], 0, 0, 0);
        acc[4 + mt][nt] = __builtin_amdgcn_mfma_f32_16x16x32_bf16(a[mt][1], bl[nt][1], acc[4 + mt][nt], 0, 0, 0);
      }
    SYNC_EXIT();
    // ---- P4: stage Bh1(t+2) -> buf; counted vmcnt(6) = 3 half-tiles in flight
    if (t + 2 < NT) {
      STG_B(1, t + 2, buf);
      asm volatile("s_waitcnt vmcnt(6)" ::: "memory");  // tile t+1 resident
    } else {
      asm volatile("s_waitcnt vmcnt(0)" ::: "memory");  // tail drain
    }
    SYNC_ENTER();
#pragma unroll
    for (int mt = 0; mt < 4; ++mt)
#pragma unroll
      for (int nt = 0; nt < 2; ++nt) {
        acc[4 + mt][2 + nt] = __builtin_amdgcn_mfma_f32_16x16x32_bf16(a[mt][0], bh[nt][0], acc[4 + mt][2 + nt], 0, 0, 0);
        acc[4 + mt][2 + nt] = __builtin_amdgcn_mfma_f32_16x16x32_bf16(a[mt][1], bh[nt][1], acc[4 + mt][2 + nt], 0, 0, 0);
      }
    SYNC_EXIT();
  }

  // ---- LoRA second stage as ONE extra MFMA K-step (k=16..31 zero-padded).
  // Pack inter rows / lora_b cols to bf16 into LDS [256][128B], swz (r&7)<<4.
  __syncthreads();
  const int adapter = load_adapter(adapters, row0 >> 11);
  {
    const int r = tid & 255;
    const float* src = (tid < 256)
        ? (inter + (size_t)(row0 + r) * RANK)
        : (lora_b + ((size_t)adapter * N_DIM + (col0 + r)) * RANK);
    char* dst = lds + ((tid < 256) ? 0 : 32768) + r * 128;
    const float4 v0 = ((const float4*)src)[0];
    const float4 v1 = ((const float4*)src)[1];
    const float4 v2 = ((const float4*)src)[2];
    const float4 v3 = ((const float4*)src)[3];
    uint4 p0, p1;
    p0.x = pk2(v0.x, v0.y); p0.y = pk2(v0.z, v0.w);
    p0.z = pk2(v1.x, v1.y); p0.w = pk2(v1.z, v1.w);
    p1.x = pk2(v2.x, v2.y); p1.y = pk2(v2.z, v2.w);
    p1.z = pk2(v3.x, v3.y); p1.w = pk2(v3.z, v3.w);
    const int sw = (r & 7) << 4;
    *(uint4*)(dst + (0  ^ sw)) = p0;
    *(uint4*)(dst + (16 ^ sw)) = p1;
    uint4 z = make_uint4(0u, 0u, 0u, 0u);
    *(uint4*)(dst + (32 ^ sw)) = z;
    *(uint4*)(dst + (48 ^ sw)) = z;
  }
  __syncthreads();
  {
    short8 la[8], lb[4];
#pragma unroll
    for (int mt = 0; mt < 8; ++mt) {
      const int rl = (mt < 4 ? wm * 64 + mt * 16 : 128 + wm * 64 + (mt - 4) * 16) + fr;
      la[mt] = *(const short8*)(lds + rl * 128 + ((fq * 16) ^ swz));
    }
#pragma unroll
    for (int nt = 0; nt < 4; ++nt) {
      const int cl = (nt < 2 ? wn * 32 + nt * 16 : 128 + wn * 32 + (nt - 2) * 16) + fr;
      lb[nt] = *(const short8*)(lds + 32768 + cl * 128 + ((fq * 16) ^ swz));
    }
#pragma unroll
    for (int mt = 0; mt < 8; ++mt)
#pragma unroll
      for (int nt = 0; nt < 4; ++nt)
        acc[mt][nt] = __builtin_amdgcn_mfma_f32_16x16x32_bf16(la[mt], lb[nt], acc[mt][nt], 0, 0, 0);
  }

  // ---- epilogue: + bias, store (C/D: col=lane&15, row=fq*4+j)
#pragma unroll
  for (int nt = 0; nt < 4; ++nt) {
    const int col = col0 + (nt < 2 ? wn * 32 + nt * 16 : 128 + wn * 32 + (nt - 2) * 16) + fr;
    const float bv = bias[col];
#pragma unroll
    for (int mt = 0; mt < 8; ++mt) {
      const int row = row0 + (mt < 4 ? wm * 64 + mt * 16 : 128 + wm * 64 + (mt - 4) * 16) + fq * 4;
      float* op = out + (size_t)row * N_DIM + col;
#pragma unroll
      for (int j = 0; j < 4; ++j)
        op[(size_t)j * N_DIM] = acc[mt][nt][j] + bv;
    }
  }
}

extern "C" void kernel_launch(void* const* d_in, const int* in_sizes, int n_in,
                              void* d_out, int out_size, void* d_ws, size_t ws_size,
                              hipStream_t stream) {
  const float* x      = (const float*)d_in[0];
  const float* W      = (const float*)d_in[1];
  const float* bias   = (const float*)d_in[2];
  const float* lora_a = (const float*)d_in[3];
  const float* lora_b = (const float*)d_in[4];
  const int*   aidx   = (const int*)d_in[5];
  float* out = (float*)d_out;

  const size_t xbf_bytes = (size_t)M_DIM * DIN * 2;   // 128 MiB
  const size_t wbf_bytes = (size_t)N_DIM * DIN * 2;   //  32 MiB
  unsigned short* xbf = (unsigned short*)d_ws;
  unsigned short* wbf = (unsigned short*)((char*)d_ws + xbf_bytes);
  float* inter = (float*)((char*)d_ws + xbf_bytes + wbf_bytes);  // 1 MiB

  static bool attr_set = false;
  if (!attr_set) {
    hipFuncSetAttribute((const void*)gemm256,
                        hipFuncAttributeMaxDynamicSharedMemorySize, LDS_BYTES);
    attr_set = true;
  }

  conv_stream<<<dim3((size_t)N_DIM * DIN / (256 * 8)), dim3(256), 0, stream>>>(W, wbf);
  conv_stream<<<dim3((size_t)M_DIM * DIN / (256 * 8)), dim3(256), 0, stream>>>(x, xbf);
  hipMemsetAsync(inter, 0, (size_t)M_DIM * RANK * sizeof(float), stream);
  inter16<<<dim3(M_DIM / 16, 2), dim3(256), 0, stream>>>(xbf, lora_a, aidx, inter);
  gemm256<<<dim3(1024), dim3(512), LDS_BYTES, stream>>>(
      xbf, wbf, bias, inter, lora_b, aidx, out);
}

// Round 3
// 917.962 us; speedup vs baseline: 1.2271x; 1.0629x over previous
//
#include <hip/hip_runtime.h>

// LoRA Linear: out = x @ W^T + bias + (x @ a[idx]^T) @ b[idx]^T
// B=8, S=2048, D_IN=D_OUT=4096, RANK=16, N_ADAPTERS=8.
// R5 (= R4 with compile fix): gemm256 barrier halving. 2 barriers/phase ->
//     single end-of-phase barrier (4/K-tile). Hazard proof: every staged
//     region's prior readers completed before the previous phase's end-barrier
//     (per-wave lgkm waits precede MFMA precede barrier); tile-resident RAW is
//     carried by per-wave vmcnt(6) at P4 + P4 barrier. Blanket lgkmcnt(0)
//     dropped -- compiler emits fine-grained partial waits. NT loads in the
//     converters (fp32 read-once) + NT stores for out (write-once) keep the
//     bf16 panels L3-resident. NT builtins need ext-vector types, not
//     HIP_vector_type (R4's compile error).
// Workspace: x_bf16 128MiB + W_bf16 32MiB + inter 1MiB = 161MiB (unchanged).

#define DIN     4096
#define DOUT    4096
#define RANK    16
#define M_DIM   16384   // B*S
#define K_DIM   DIN
#define N_DIM   DOUT
#define BK      64
#define NT      (K_DIM / BK)     // 64 K-tiles
#define LDS_BYTES 131072

typedef __attribute__((ext_vector_type(8))) short  short8;
typedef __attribute__((ext_vector_type(4))) float  floatx4;
typedef __attribute__((ext_vector_type(4))) unsigned int uintx4;

__device__ __forceinline__ unsigned short f2bf(float f) {
  union { float f; unsigned int u; } v; v.f = f;
  return (unsigned short)((v.u + 0x7FFFu + ((v.u >> 16) & 1u)) >> 16);
}
__device__ __forceinline__ unsigned int pk2(float a, float b) {
  return (unsigned int)f2bf(a) | ((unsigned int)f2bf(b) << 16);
}

// adapter_indices is int64 in the reference; harness contract says int32.
// int64 little-endian with values<8 looks like [v0,0,v1,0,...] as int32.
__device__ __forceinline__ int load_adapter(const int* __restrict__ p, int b) {
  bool i64 = (p[1] == 0) & (p[3] == 0) & (p[5] == 0) & (p[7] == 0);
  return i64 ? p[2 * b] : p[b];
}

__device__ __forceinline__ void async16(const unsigned short* g, void* s) {
  __builtin_amdgcn_global_load_lds(
      (const __attribute__((address_space(1))) void*)g,
      (__attribute__((address_space(3))) void*)s, 16, 0, 0);
}

// ---------- kernel 1: fp32 -> bf16 streaming (used for both W and x) ----------
__global__ __launch_bounds__(256) void conv_stream(const float* __restrict__ w,
                                                   unsigned short* __restrict__ wbf) {
  size_t base = ((size_t)blockIdx.x * 256 + threadIdx.x) * 8;
  const floatx4* src = (const floatx4*)(w + base);
  floatx4 f0 = __builtin_nontemporal_load(src);      // read-once: bypass caches
  floatx4 f1 = __builtin_nontemporal_load(src + 1);
  uintx4 p;
  p.x = pk2(f0.x, f0.y); p.y = pk2(f0.z, f0.w);
  p.z = pk2(f1.x, f1.y); p.w = pk2(f1.z, f1.w);
  *(uintx4*)(wbf + base) = p;                        // re-read later: keep cached
}

// ---------- kernel 2: inter = x @ a^T via MFMA, K split 2 ways across grid ----
// grid (M/16, 2), 256 thr / 4 waves. Wave w: k in [blockIdx.y*2048 + w*512, +512).
// Block reduce 4 waves in LDS; wave 0 atomicAdds (2 commutative adds -> exact).
__global__ __launch_bounds__(256) void inter16(
    const unsigned short* __restrict__ xbf,
    const float* __restrict__ lora_a,
    const int* __restrict__ adapters,
    float* __restrict__ inter) {
  __shared__ floatx4 red[4][64];
  const int tid = threadIdx.x, wave = tid >> 6, lane = tid & 63;
  const int fr = lane & 15, fq = lane >> 4;
  const int row0 = blockIdx.x * 16;
  const int adapter = load_adapter(adapters, row0 >> 11);  // 2048 rows/batch
  const unsigned short* xp = xbf + (size_t)(row0 + fr) * DIN;
  const float* ap = lora_a + ((size_t)adapter * RANK + fr) * DIN;
  floatx4 acc = {};
  const int kbeg = blockIdx.y * 2048 + wave * 512;
#pragma unroll 2
  for (int k0 = kbeg; k0 < kbeg + 512; k0 += 32) {
    const int k = k0 + fq * 8;
    short8 xf = *(const short8*)(xp + k);      // x already bf16
    floatx4 b0 = *(const floatx4*)(ap + k);
    floatx4 b1 = *(const floatx4*)(ap + k + 4);
    uintx4 bpk;
    bpk.x = pk2(b0.x, b0.y); bpk.y = pk2(b0.z, b0.w);
    bpk.z = pk2(b1.x, b1.y); bpk.w = pk2(b1.z, b1.w);
    acc = __builtin_amdgcn_mfma_f32_16x16x32_bf16(xf, *(short8*)&bpk, acc, 0, 0, 0);
  }
  red[wave][lane] = acc;
  __syncthreads();
  if (wave == 0) {
    floatx4 s = red[0][lane] + red[1][lane] + red[2][lane] + red[3][lane];
    // C/D layout: col(rank)=lane&15, row=fq*4+j
#pragma unroll
    for (int j = 0; j < 4; ++j)
      atomicAdd(&inter[(size_t)(row0 + fq * 4 + j) * RANK + fr], s[j]);
  }
}

// ---------- kernel 3: 256x256 4-phase/1-barrier bf16 GEMM + LoRA + bias -------
#define PHASE_END() do {                                    \
    __builtin_amdgcn_sched_barrier(0);                      \
    __builtin_amdgcn_s_barrier();                           \
    __builtin_amdgcn_sched_barrier(0); } while (0)

__global__ __launch_bounds__(512, 2) void gemm256(
    const unsigned short* __restrict__ A,    // x bf16 [M,K]
    const unsigned short* __restrict__ Bw,   // W bf16 [N,K] (row-major = B^T)
    const float* __restrict__ bias,          // [N]
    const float* __restrict__ inter,         // [M,16] fp32
    const float* __restrict__ lora_b,        // [8, N, 16] fp32
    const int* __restrict__ adapters,
    float* __restrict__ out) {               // [M,N] fp32
  extern __shared__ char lds[];
  const int tid  = threadIdx.x;
  const int lane = tid & 63, wave = tid >> 6;
  const int wm = wave >> 2, wn = wave & 3;   // 2 x 4 wave grid

  // T1: bijective XCD swizzle (1024 % 8 == 0)
  const int wg   = ((int)blockIdx.x & 7) * 128 + ((int)blockIdx.x >> 3);
  const int row0 = (wg >> 4) * 256;          // 64 M-tiles
  const int col0 = (wg & 15) * 256;          // 16 N-tiles (fastest: share A-panel)

  // ---- staging geometry. global_load_lds writes linear (base + lane*16B), so
  // the T2 swizzle (byte ^= (row&7)<<4) is applied by permuting the GLOBAL src:
  // LDS slot granule g' = lane&7 at row (wave*16 + lane>>3) holds source
  // k-granule g = g' ^ (row&7) = (lane&7) ^ (lane>>3).
  const int sg = (lane & 7) ^ (lane >> 3);
  const int sr = wave * 16 + (lane >> 3);
  const unsigned short* pA0 = A  + (size_t)(row0 + sr) * K_DIM + sg * 8;
  const unsigned short* pB0 = Bw + (size_t)(col0 + sr) * K_DIM + sg * 8;
  char* const dA0 = lds + wave * 2048;       // wave-uniform dest base

#define STG_A(h, kt, buf) do {                                            \
    const unsigned short* _p = pA0 + (size_t)(h) * 128 * K_DIM + (kt) * BK; \
    char* _d = dA0 + (buf) * 65536 + (h) * 16384;                         \
    async16(_p, _d);                                                      \
    async16(_p + (size_t)8 * K_DIM, _d + 1024); } while (0)
#define STG_B(h, kt, buf) do {                                            \
    const unsigned short* _p = pB0 + (size_t)(h) * 128 * K_DIM + (kt) * BK; \
    char* _d = dA0 + 32768 + (buf) * 65536 + (h) * 16384;                 \
    async16(_p, _d);                                                      \
    async16(_p + (size_t)8 * K_DIM, _d + 1024); } while (0)

  // ---- fragment read geometry (16x16x32: A[m=lane&15][k=(lane>>4)*8+j])
  const int fr = lane & 15, fq = lane >> 4;
  const int swz = (fr & 7) << 4;
  const int kb0 = (fq * 16) ^ swz;           // ks=0 byte col (swizzled)
  const int kb1 = (64 + fq * 16) ^ swz;      // ks=1
  const int ar = wm * 64 + fr;               // A row base: +mt*16, +128 for hi
  const int br = wn * 32 + fr;               // B row base: +nt*16, +128 for hi

  floatx4 acc[8][4] = {};
  short8 a[4][2], bl[2][2], bh[2][2];

  // ---- prologue: tile0 all 4 halves -> buf0; {Ah0,Bh0,Bh1}(tile1) -> buf1
  STG_A(0, 0, 0); STG_B(0, 0, 0); STG_B(1, 0, 0); STG_A(1, 0, 0);
  STG_A(0, 1, 1); STG_B(0, 1, 1); STG_B(1, 1, 1);
  asm volatile("s_waitcnt vmcnt(6)" ::: "memory");   // tile0 resident
  __builtin_amdgcn_sched_barrier(0);
  __builtin_amdgcn_s_barrier();
  __builtin_amdgcn_sched_barrier(0);

  for (int t = 0; t < NT; ++t) {
    const int buf = t & 1, nbuf = buf ^ 1;
    const char* ab = lds + buf * 65536;
    const char* bb = ab + 32768;
    // ---- P1: read A-lo + B-lo; stage Ah1(t+1)->nbuf; MFMA Q00; barrier.
    //      (Ah1(nbuf) last read in t-1's P3, ordered by t-1 P3 end-barrier.)
#pragma unroll
    for (int mt = 0; mt < 4; ++mt) {
      a[mt][0] = *(const short8*)(ab + (ar + mt * 16) * 128 + kb0);
      a[mt][1] = *(const short8*)(ab + (ar + mt * 16) * 128 + kb1);
    }
#pragma unroll
    for (int nt = 0; nt < 2; ++nt) {
      bl[nt][0] = *(const short8*)(bb + (br + nt * 16) * 128 + kb0);
      bl[nt][1] = *(const short8*)(bb + (br + nt * 16) * 128 + kb1);
    }
    if (t + 1 < NT) STG_A(1, t + 1, nbuf);
    __builtin_amdgcn_s_setprio(1);
#pragma unroll
    for (int mt = 0; mt < 4; ++mt)
#pragma unroll
      for (int nt = 0; nt < 2; ++nt) {
        acc[mt][nt] = __builtin_amdgcn_mfma_f32_16x16x32_bf16(a[mt][0], bl[nt][0], acc[mt][nt], 0, 0, 0);
        acc[mt][nt] = __builtin_amdgcn_mfma_f32_16x16x32_bf16(a[mt][1], bl[nt][1], acc[mt][nt], 0, 0, 0);
      }
    __builtin_amdgcn_s_setprio(0);
    PHASE_END();
    // ---- P2: read B-hi; stage Ah0(t+2)->buf (A-lo(t) reads drained @P1 bar).
#pragma unroll
    for (int nt = 0; nt < 2; ++nt) {
      bh[nt][0] = *(const short8*)(bb + (128 + br + nt * 16) * 128 + kb0);
      bh[nt][1] = *(const short8*)(bb + (128 + br + nt * 16) * 128 + kb1);
    }
    if (t + 2 < NT) STG_A(0, t + 2, buf);
    __builtin_amdgcn_s_setprio(1);
#pragma unroll
    for (int mt = 0; mt < 4; ++mt)
#pragma unroll
      for (int nt = 0; nt < 2; ++nt) {
        acc[mt][2 + nt] = __builtin_amdgcn_mfma_f32_16x16x32_bf16(a[mt][0], bh[nt][0], acc[mt][2 + nt], 0, 0, 0);
        acc[mt][2 + nt] = __builtin_amdgcn_mfma_f32_16x16x32_bf16(a[mt][1], bh[nt][1], acc[mt][2 + nt], 0, 0, 0);
      }
    __builtin_amdgcn_s_setprio(0);
    PHASE_END();
    // ---- P3: read A-hi (reuse a[]); stage Bh0(t+2)->buf; MFMA Q10.
#pragma unroll
    for (int mt = 0; mt < 4; ++mt) {
      a[mt][0] = *(const short8*)(ab + (128 + ar + mt * 16) * 128 + kb0);
      a[mt][1] = *(const short8*)(ab + (128 + ar + mt * 16) * 128 + kb1);
    }
    if (t + 2 < NT) STG_B(0, t + 2, buf);
    __builtin_amdgcn_s_setprio(1);
#pragma unroll
    for (int mt = 0; mt < 4; ++mt)
#pragma unroll
      for (int nt = 0; nt < 2; ++nt) {
        acc[4 + mt][nt] = __builtin_amdgcn_mfma_f32_16x16x32_bf16(a[mt][0], bl[nt][0], acc[4 + mt][nt], 0, 0, 0);
        acc[4 + mt][nt] = __builtin_amdgcn_mfma_f32_16x16x32_bf16(a[mt][1], bl[nt][1], acc[4 + mt][nt], 0, 0, 0);
      }
    __builtin_amdgcn_s_setprio(0);
    PHASE_END();
    // ---- P4: stage Bh1(t+2)->buf; vmcnt(6) => tile t+1 fully resident after
    //      the barrier (outstanding 6 = the three t+2 half-tiles). MFMA Q11.
    if (t + 2 < NT) STG_B(1, t + 2, buf);
    __builtin_amdgcn_s_setprio(1);
#pragma unroll
    for (int mt = 0; mt < 4; ++mt)
#pragma unroll
      for (int nt = 0; nt < 2; ++nt) {
        acc[4 + mt][2 + nt] = __builtin_amdgcn_mfma_f32_16x16x32_bf16(a[mt][0], bh[nt][0], acc[4 + mt][2 + nt], 0, 0, 0);
        acc[4 + mt][2 + nt] = __builtin_amdgcn_mfma_f32_16x16x32_bf16(a[mt][1], bh[nt][1], acc[4 + mt][2 + nt], 0, 0, 0);
      }
    __builtin_amdgcn_s_setprio(0);
    __builtin_amdgcn_sched_barrier(0);
    if (t + 2 < NT) {
      asm volatile("s_waitcnt vmcnt(6)" ::: "memory");
    } else {
      asm volatile("s_waitcnt vmcnt(0)" ::: "memory");  // tail drain
    }
    __builtin_amdgcn_sched_barrier(0);
    __builtin_amdgcn_s_barrier();
    __builtin_amdgcn_sched_barrier(0);
  }

  // ---- LoRA second stage as ONE extra MFMA K-step (k=16..31 zero-padded).
  // Pack inter rows / lora_b cols to bf16 into LDS [256][128B], swz (r&7)<<4.
  __syncthreads();
  const int adapter = load_adapter(adapters, row0 >> 11);
  {
    const int r = tid & 255;
    const float* src = (tid < 256)
        ? (inter + (size_t)(row0 + r) * RANK)
        : (lora_b + ((size_t)adapter * N_DIM + (col0 + r)) * RANK);
    char* dst = lds + ((tid < 256) ? 0 : 32768) + r * 128;
    const floatx4 v0 = ((const floatx4*)src)[0];
    const floatx4 v1 = ((const floatx4*)src)[1];
    const floatx4 v2 = ((const floatx4*)src)[2];
    const floatx4 v3 = ((const floatx4*)src)[3];
    uintx4 p0, p1;
    p0.x = pk2(v0.x, v0.y); p0.y = pk2(v0.z, v0.w);
    p0.z = pk2(v1.x, v1.y); p0.w = pk2(v1.z, v1.w);
    p1.x = pk2(v2.x, v2.y); p1.y = pk2(v2.z, v2.w);
    p1.z = pk2(v3.x, v3.y); p1.w = pk2(v3.z, v3.w);
    const int sw = (r & 7) << 4;
    *(uintx4*)(dst + (0  ^ sw)) = p0;
    *(uintx4*)(dst + (16 ^ sw)) = p1;
    uintx4 z = {0u, 0u, 0u, 0u};
    *(uintx4*)(dst + (32 ^ sw)) = z;
    *(uintx4*)(dst + (48 ^ sw)) = z;
  }
  __syncthreads();
  {
    short8 la[8], lb[4];
#pragma unroll
    for (int mt = 0; mt < 8; ++mt) {
      const int rl = (mt < 4 ? wm * 64 + mt * 16 : 128 + wm * 64 + (mt - 4) * 16) + fr;
      la[mt] = *(const short8*)(lds + rl * 128 + ((fq * 16) ^ swz));
    }
#pragma unroll
    for (int nt = 0; nt < 4; ++nt) {
      const int cl = (nt < 2 ? wn * 32 + nt * 16 : 128 + wn * 32 + (nt - 2) * 16) + fr;
      lb[nt] = *(const short8*)(lds + 32768 + cl * 128 + ((fq * 16) ^ swz));
    }
#pragma unroll
    for (int mt = 0; mt < 8; ++mt)
#pragma unroll
      for (int nt = 0; nt < 4; ++nt)
        acc[mt][nt] = __builtin_amdgcn_mfma_f32_16x16x32_bf16(la[mt], lb[nt], acc[mt][nt], 0, 0, 0);
  }

  // ---- epilogue: + bias, NT store (out is write-once; don't thrash L3)
#pragma unroll
  for (int nt = 0; nt < 4; ++nt) {
    const int col = col0 + (nt < 2 ? wn * 32 + nt * 16 : 128 + wn * 32 + (nt - 2) * 16) + fr;
    const float bv = bias[col];
#pragma unroll
    for (int mt = 0; mt < 8; ++mt) {
      const int row = row0 + (mt < 4 ? wm * 64 + mt * 16 : 128 + wm * 64 + (mt - 4) * 16) + fq * 4;
      float* op = out + (size_t)row * N_DIM + col;
#pragma unroll
      for (int j = 0; j < 4; ++j)
        __builtin_nontemporal_store(acc[mt][nt][j] + bv, op + (size_t)j * N_DIM);
    }
  }
}

extern "C" void kernel_launch(void* const* d_in, const int* in_sizes, int n_in,
                              void* d_out, int out_size, void* d_ws, size_t ws_size,
                              hipStream_t stream) {
  const float* x      = (const float*)d_in[0];
  const float* W      = (const float*)d_in[1];
  const float* bias   = (const float*)d_in[2];
  const float* lora_a = (const float*)d_in[3];
  const float* lora_b = (const float*)d_in[4];
  const int*   aidx   = (const int*)d_in[5];
  float* out = (float*)d_out;

  const size_t xbf_bytes = (size_t)M_DIM * DIN * 2;   // 128 MiB
  const size_t wbf_bytes = (size_t)N_DIM * DIN * 2;   //  32 MiB
  unsigned short* xbf = (unsigned short*)d_ws;
  unsigned short* wbf = (unsigned short*)((char*)d_ws + xbf_bytes);
  float* inter = (float*)((char*)d_ws + xbf_bytes + wbf_bytes);  // 1 MiB

  static bool attr_set = false;
  if (!attr_set) {
    (void)hipFuncSetAttribute((const void*)gemm256,
                              hipFuncAttributeMaxDynamicSharedMemorySize, LDS_BYTES);
    attr_set = true;
  }

  conv_stream<<<dim3((size_t)N_DIM * DIN / (256 * 8)), dim3(256), 0, stream>>>(W, wbf);
  conv_stream<<<dim3((size_t)M_DIM * DIN / (256 * 8)), dim3(256), 0, stream>>>(x, xbf);
  (void)hipMemsetAsync(inter, 0, (size_t)M_DIM * RANK * sizeof(float), stream);
  inter16<<<dim3(M_DIM / 16, 2), dim3(256), 0, stream>>>(xbf, lora_a, aidx, inter);
  gemm256<<<dim3(1024), dim3(512), LDS_BYTES, stream>>>(
      xbf, wbf, bias, inter, lora_b, aidx, out);
}

// Round 4
// 911.587 us; speedup vs baseline: 1.2357x; 1.0070x over previous
//
#include <hip/hip_runtime.h>

// LoRA Linear: out = x @ W^T + bias + (x @ a[idx]^T) @ b[idx]^T
// B=8, S=2048, D_IN=D_OUT=4096, RANK=16, N_ADAPTERS=8.
// R6: gemm256 2-phase K-tile (was 4). Phase A: ds_read A-lo + ALL B (16 b128),
//     stage Ah1(t+1)->nbuf, 32 MFMA, barrier. Phase B: ds_read A-hi, stage
//     {Ah0,Bh0,Bh1}(t+2)->buf, 32 MFMA, vmcnt(6), barrier. Hazard proof: every
//     staged region's prior readers completed before the single intervening
//     barrier; vmcnt(6) leaves exactly the three t+2 half-tiles outstanding.
//     +32 VGPR for b[4][2] (acc128+a32+b32+addr ~210 < 256 cap; LDS already
//     limits to 1 block/CU so VGPR is free headroom).
// Workspace: x_bf16 128MiB + W_bf16 32MiB + inter 1MiB = 161MiB (unchanged).

#define DIN     4096
#define DOUT    4096
#define RANK    16
#define M_DIM   16384   // B*S
#define K_DIM   DIN
#define N_DIM   DOUT
#define BK      64
#define NT      (K_DIM / BK)     // 64 K-tiles
#define LDS_BYTES 131072

typedef __attribute__((ext_vector_type(8))) short  short8;
typedef __attribute__((ext_vector_type(4))) float  floatx4;
typedef __attribute__((ext_vector_type(4))) unsigned int uintx4;

__device__ __forceinline__ unsigned short f2bf(float f) {
  union { float f; unsigned int u; } v; v.f = f;
  return (unsigned short)((v.u + 0x7FFFu + ((v.u >> 16) & 1u)) >> 16);
}
__device__ __forceinline__ unsigned int pk2(float a, float b) {
  return (unsigned int)f2bf(a) | ((unsigned int)f2bf(b) << 16);
}

// adapter_indices is int64 in the reference; harness contract says int32.
// int64 little-endian with values<8 looks like [v0,0,v1,0,...] as int32.
__device__ __forceinline__ int load_adapter(const int* __restrict__ p, int b) {
  bool i64 = (p[1] == 0) & (p[3] == 0) & (p[5] == 0) & (p[7] == 0);
  return i64 ? p[2 * b] : p[b];
}

__device__ __forceinline__ void async16(const unsigned short* g, void* s) {
  __builtin_amdgcn_global_load_lds(
      (const __attribute__((address_space(1))) void*)g,
      (__attribute__((address_space(3))) void*)s, 16, 0, 0);
}

// ---------- kernel 1: fp32 -> bf16 streaming (used for both W and x) ----------
__global__ __launch_bounds__(256) void conv_stream(const float* __restrict__ w,
                                                   unsigned short* __restrict__ wbf) {
  size_t base = ((size_t)blockIdx.x * 256 + threadIdx.x) * 8;
  const floatx4* src = (const floatx4*)(w + base);
  floatx4 f0 = __builtin_nontemporal_load(src);      // read-once: bypass caches
  floatx4 f1 = __builtin_nontemporal_load(src + 1);
  uintx4 p;
  p.x = pk2(f0.x, f0.y); p.y = pk2(f0.z, f0.w);
  p.z = pk2(f1.x, f1.y); p.w = pk2(f1.z, f1.w);
  *(uintx4*)(wbf + base) = p;                        // re-read later: keep cached
}

// ---------- kernel 2: inter = x @ a^T via MFMA, K split 2 ways across grid ----
// grid (M/16, 2), 256 thr / 4 waves. Wave w: k in [blockIdx.y*2048 + w*512, +512).
// Block reduce 4 waves in LDS; wave 0 atomicAdds (2 commutative adds -> exact).
__global__ __launch_bounds__(256) void inter16(
    const unsigned short* __restrict__ xbf,
    const float* __restrict__ lora_a,
    const int* __restrict__ adapters,
    float* __restrict__ inter) {
  __shared__ floatx4 red[4][64];
  const int tid = threadIdx.x, wave = tid >> 6, lane = tid & 63;
  const int fr = lane & 15, fq = lane >> 4;
  const int row0 = blockIdx.x * 16;
  const int adapter = load_adapter(adapters, row0 >> 11);  // 2048 rows/batch
  const unsigned short* xp = xbf + (size_t)(row0 + fr) * DIN;
  const float* ap = lora_a + ((size_t)adapter * RANK + fr) * DIN;
  floatx4 acc = {};
  const int kbeg = blockIdx.y * 2048 + wave * 512;
#pragma unroll 2
  for (int k0 = kbeg; k0 < kbeg + 512; k0 += 32) {
    const int k = k0 + fq * 8;
    short8 xf = *(const short8*)(xp + k);      // x already bf16
    floatx4 b0 = *(const floatx4*)(ap + k);
    floatx4 b1 = *(const floatx4*)(ap + k + 4);
    uintx4 bpk;
    bpk.x = pk2(b0.x, b0.y); bpk.y = pk2(b0.z, b0.w);
    bpk.z = pk2(b1.x, b1.y); bpk.w = pk2(b1.z, b1.w);
    acc = __builtin_amdgcn_mfma_f32_16x16x32_bf16(xf, *(short8*)&bpk, acc, 0, 0, 0);
  }
  red[wave][lane] = acc;
  __syncthreads();
  if (wave == 0) {
    floatx4 s = red[0][lane] + red[1][lane] + red[2][lane] + red[3][lane];
    // C/D layout: col(rank)=lane&15, row=fq*4+j
#pragma unroll
    for (int j = 0; j < 4; ++j)
      atomicAdd(&inter[(size_t)(row0 + fq * 4 + j) * RANK + fr], s[j]);
  }
}

// ---------- kernel 3: 256x256 2-phase/K-tile bf16 GEMM + LoRA + bias ----------
#define PHASE_END() do {                                    \
    __builtin_amdgcn_sched_barrier(0);                      \
    __builtin_amdgcn_s_barrier();                           \
    __builtin_amdgcn_sched_barrier(0); } while (0)

__global__ __launch_bounds__(512, 2) void gemm256(
    const unsigned short* __restrict__ A,    // x bf16 [M,K]
    const unsigned short* __restrict__ Bw,   // W bf16 [N,K] (row-major = B^T)
    const float* __restrict__ bias,          // [N]
    const float* __restrict__ inter,         // [M,16] fp32
    const float* __restrict__ lora_b,        // [8, N, 16] fp32
    const int* __restrict__ adapters,
    float* __restrict__ out) {               // [M,N] fp32
  extern __shared__ char lds[];
  const int tid  = threadIdx.x;
  const int lane = tid & 63, wave = tid >> 6;
  const int wm = wave >> 2, wn = wave & 3;   // 2 x 4 wave grid

  // T1: bijective XCD swizzle (1024 % 8 == 0)
  const int wg   = ((int)blockIdx.x & 7) * 128 + ((int)blockIdx.x >> 3);
  const int row0 = (wg >> 4) * 256;          // 64 M-tiles
  const int col0 = (wg & 15) * 256;          // 16 N-tiles (fastest: share A-panel)

  // ---- staging geometry. global_load_lds writes linear (base + lane*16B), so
  // the T2 swizzle (byte ^= (row&7)<<4) is applied by permuting the GLOBAL src:
  // LDS slot granule g' = lane&7 at row (wave*16 + lane>>3) holds source
  // k-granule g = g' ^ (row&7) = (lane&7) ^ (lane>>3).
  const int sg = (lane & 7) ^ (lane >> 3);
  const int sr = wave * 16 + (lane >> 3);
  const unsigned short* pA0 = A  + (size_t)(row0 + sr) * K_DIM + sg * 8;
  const unsigned short* pB0 = Bw + (size_t)(col0 + sr) * K_DIM + sg * 8;
  char* const dA0 = lds + wave * 2048;       // wave-uniform dest base

#define STG_A(h, kt, buf) do {                                            \
    const unsigned short* _p = pA0 + (size_t)(h) * 128 * K_DIM + (kt) * BK; \
    char* _d = dA0 + (buf) * 65536 + (h) * 16384;                         \
    async16(_p, _d);                                                      \
    async16(_p + (size_t)8 * K_DIM, _d + 1024); } while (0)
#define STG_B(h, kt, buf) do {                                            \
    const unsigned short* _p = pB0 + (size_t)(h) * 128 * K_DIM + (kt) * BK; \
    char* _d = dA0 + 32768 + (buf) * 65536 + (h) * 16384;                 \
    async16(_p, _d);                                                      \
    async16(_p + (size_t)8 * K_DIM, _d + 1024); } while (0)

  // ---- fragment read geometry (16x16x32: A[m=lane&15][k=(lane>>4)*8+j])
  const int fr = lane & 15, fq = lane >> 4;
  const int swz = (fr & 7) << 4;
  const int kb0 = (fq * 16) ^ swz;           // ks=0 byte col (swizzled)
  const int kb1 = (64 + fq * 16) ^ swz;      // ks=1
  const int ar = wm * 64 + fr;               // A row base: +mt*16, +128 for hi
  const int br = wn * 32 + fr;               // B row base: +nt*16, +128 for hi

  floatx4 acc[8][4] = {};
  short8 a[4][2], b[4][2];

  // ---- prologue: tile0 all 4 halves -> buf0; {Ah0,Bh0,Bh1}(tile1) -> buf1
  STG_A(0, 0, 0); STG_B(0, 0, 0); STG_B(1, 0, 0); STG_A(1, 0, 0);
  STG_A(0, 1, 1); STG_B(0, 1, 1); STG_B(1, 1, 1);
  asm volatile("s_waitcnt vmcnt(6)" ::: "memory");   // tile0 resident
  __builtin_amdgcn_sched_barrier(0);
  __builtin_amdgcn_s_barrier();
  __builtin_amdgcn_sched_barrier(0);

  for (int t = 0; t < NT; ++t) {
    const int buf = t & 1, nbuf = buf ^ 1;
    const char* ab = lds + buf * 65536;
    const char* bb = ab + 32768;
    // ---- Phase A: read A-lo + ALL B; stage Ah1(t+1)->nbuf; 32 MFMA; barrier.
    //      (Ah1(nbuf) last read in t-1's Phase B, ordered by its end barrier.)
    //      b[0]=br, b[1]=br+16, b[2]=128+br, b[3]=128+br+16 (matches epilogue).
#pragma unroll
    for (int mt = 0; mt < 4; ++mt) {
      a[mt][0] = *(const short8*)(ab + (ar + mt * 16) * 128 + kb0);
      a[mt][1] = *(const short8*)(ab + (ar + mt * 16) * 128 + kb1);
    }
#pragma unroll
    for (int nt = 0; nt < 2; ++nt) {
      b[nt][0]     = *(const short8*)(bb + (br + nt * 16) * 128 + kb0);
      b[nt][1]     = *(const short8*)(bb + (br + nt * 16) * 128 + kb1);
      b[2 + nt][0] = *(const short8*)(bb + (128 + br + nt * 16) * 128 + kb0);
      b[2 + nt][1] = *(const short8*)(bb + (128 + br + nt * 16) * 128 + kb1);
    }
    if (t + 1 < NT) STG_A(1, t + 1, nbuf);
    __builtin_amdgcn_s_setprio(1);
#pragma unroll
    for (int mt = 0; mt < 4; ++mt)
#pragma unroll
      for (int nt = 0; nt < 4; ++nt) {
        acc[mt][nt] = __builtin_amdgcn_mfma_f32_16x16x32_bf16(a[mt][0], b[nt][0], acc[mt][nt], 0, 0, 0);
        acc[mt][nt] = __builtin_amdgcn_mfma_f32_16x16x32_bf16(a[mt][1], b[nt][1], acc[mt][nt], 0, 0, 0);
      }
    __builtin_amdgcn_s_setprio(0);
    PHASE_END();
    // ---- Phase B: read A-hi (reuse a[]); stage {Ah0,Bh0,Bh1}(t+2)->buf
    //      (A-lo/B(t) reads all drained at Phase-A barrier; Ah0 stage targets
    //      h=0 region, A-hi reads h=1 region -- disjoint). 32 MFMA.
#pragma unroll
    for (int mt = 0; mt < 4; ++mt) {
      a[mt][0] = *(const short8*)(ab + (128 + ar + mt * 16) * 128 + kb0);
      a[mt][1] = *(const short8*)(ab + (128 + ar + mt * 16) * 128 + kb1);
    }
    if (t + 2 < NT) { STG_A(0, t + 2, buf); STG_B(0, t + 2, buf); STG_B(1, t + 2, buf); }
    __builtin_amdgcn_s_setprio(1);
#pragma unroll
    for (int mt = 0; mt < 4; ++mt)
#pragma unroll
      for (int nt = 0; nt < 4; ++nt) {
        acc[4 + mt][nt] = __builtin_amdgcn_mfma_f32_16x16x32_bf16(a[mt][0], b[nt][0], acc[4 + mt][nt], 0, 0, 0);
        acc[4 + mt][nt] = __builtin_amdgcn_mfma_f32_16x16x32_bf16(a[mt][1], b[nt][1], acc[4 + mt][nt], 0, 0, 0);
      }
    __builtin_amdgcn_s_setprio(0);
    __builtin_amdgcn_sched_barrier(0);
    if (t + 2 < NT) {
      asm volatile("s_waitcnt vmcnt(6)" ::: "memory");  // tile t+1 resident
    } else {
      asm volatile("s_waitcnt vmcnt(0)" ::: "memory");  // tail drain
    }
    __builtin_amdgcn_sched_barrier(0);
    __builtin_amdgcn_s_barrier();
    __builtin_amdgcn_sched_barrier(0);
  }

  // ---- LoRA second stage as ONE extra MFMA K-step (k=16..31 zero-padded).
  // Pack inter rows / lora_b cols to bf16 into LDS [256][128B], swz (r&7)<<4.
  __syncthreads();
  const int adapter = load_adapter(adapters, row0 >> 11);
  {
    const int r = tid & 255;
    const float* src = (tid < 256)
        ? (inter + (size_t)(row0 + r) * RANK)
        : (lora_b + ((size_t)adapter * N_DIM + (col0 + r)) * RANK);
    char* dst = lds + ((tid < 256) ? 0 : 32768) + r * 128;
    const floatx4 v0 = ((const floatx4*)src)[0];
    const floatx4 v1 = ((const floatx4*)src)[1];
    const floatx4 v2 = ((const floatx4*)src)[2];
    const floatx4 v3 = ((const floatx4*)src)[3];
    uintx4 p0, p1;
    p0.x = pk2(v0.x, v0.y); p0.y = pk2(v0.z, v0.w);
    p0.z = pk2(v1.x, v1.y); p0.w = pk2(v1.z, v1.w);
    p1.x = pk2(v2.x, v2.y); p1.y = pk2(v2.z, v2.w);
    p1.z = pk2(v3.x, v3.y); p1.w = pk2(v3.z, v3.w);
    const int sw = (r & 7) << 4;
    *(uintx4*)(dst + (0  ^ sw)) = p0;
    *(uintx4*)(dst + (16 ^ sw)) = p1;
    uintx4 z = {0u, 0u, 0u, 0u};
    *(uintx4*)(dst + (32 ^ sw)) = z;
    *(uintx4*)(dst + (48 ^ sw)) = z;
  }
  __syncthreads();
  {
    short8 la[8], lb[4];
#pragma unroll
    for (int mt = 0; mt < 8; ++mt) {
      const int rl = (mt < 4 ? wm * 64 + mt * 16 : 128 + wm * 64 + (mt - 4) * 16) + fr;
      la[mt] = *(const short8*)(lds + rl * 128 + ((fq * 16) ^ swz));
    }
#pragma unroll
    for (int nt = 0; nt < 4; ++nt) {
      const int cl = (nt < 2 ? wn * 32 + nt * 16 : 128 + wn * 32 + (nt - 2) * 16) + fr;
      lb[nt] = *(const short8*)(lds + 32768 + cl * 128 + ((fq * 16) ^ swz));
    }
#pragma unroll
    for (int mt = 0; mt < 8; ++mt)
#pragma unroll
      for (int nt = 0; nt < 4; ++nt)
        acc[mt][nt] = __builtin_amdgcn_mfma_f32_16x16x32_bf16(la[mt], lb[nt], acc[mt][nt], 0, 0, 0);
  }

  // ---- epilogue: + bias, NT store (out is write-once; don't thrash L3)
#pragma unroll
  for (int nt = 0; nt < 4; ++nt) {
    const int col = col0 + (nt < 2 ? wn * 32 + nt * 16 : 128 + wn * 32 + (nt - 2) * 16) + fr;
    const float bv = bias[col];
#pragma unroll
    for (int mt = 0; mt < 8; ++mt) {
      const int row = row0 + (mt < 4 ? wm * 64 + mt * 16 : 128 + wm * 64 + (mt - 4) * 16) + fq * 4;
      float* op = out + (size_t)row * N_DIM + col;
#pragma unroll
      for (int j = 0; j < 4; ++j)
        __builtin_nontemporal_store(acc[mt][nt][j] + bv, op + (size_t)j * N_DIM);
    }
  }
}

extern "C" void kernel_launch(void* const* d_in, const int* in_sizes, int n_in,
                              void* d_out, int out_size, void* d_ws, size_t ws_size,
                              hipStream_t stream) {
  const float* x      = (const float*)d_in[0];
  const float* W      = (const float*)d_in[1];
  const float* bias   = (const float*)d_in[2];
  const float* lora_a = (const float*)d_in[3];
  const float* lora_b = (const float*)d_in[4];
  const int*   aidx   = (const int*)d_in[5];
  float* out = (float*)d_out;

  const size_t xbf_bytes = (size_t)M_DIM * DIN * 2;   // 128 MiB
  const size_t wbf_bytes = (size_t)N_DIM * DIN * 2;   //  32 MiB
  unsigned short* xbf = (unsigned short*)d_ws;
  unsigned short* wbf = (unsigned short*)((char*)d_ws + xbf_bytes);
  float* inter = (float*)((char*)d_ws + xbf_bytes + wbf_bytes);  // 1 MiB

  static bool attr_set = false;
  if (!attr_set) {
    (void)hipFuncSetAttribute((const void*)gemm256,
                              hipFuncAttributeMaxDynamicSharedMemorySize, LDS_BYTES);
    attr_set = true;
  }

  conv_stream<<<dim3((size_t)N_DIM * DIN / (256 * 8)), dim3(256), 0, stream>>>(W, wbf);
  conv_stream<<<dim3((size_t)M_DIM * DIN / (256 * 8)), dim3(256), 0, stream>>>(x, xbf);
  (void)hipMemsetAsync(inter, 0, (size_t)M_DIM * RANK * sizeof(float), stream);
  inter16<<<dim3(M_DIM / 16, 2), dim3(256), 0, stream>>>(xbf, lora_a, aidx, inter);
  gemm256<<<dim3(1024), dim3(512), LDS_BYTES, stream>>>(
      xbf, wbf, bias, inter, lora_b, aidx, out);
}